// Round 5
// baseline (82.130 us; speedup 1.0000x reference)
//
#include <hip/hip_runtime.h>

// INT8QuantizedLinear: B=16, S=512, IN=1024, OUT=4096  (M=8192, N=4096, K=1024)
// Harness widens integer inputs: weight arrives as const int* (int32 per value).
// Round 5: m201-style fine-phase schedule. 256x256 tile, 8 waves, BK=128,
// 4 phases/K-tile x 16 MFMA, counted vmcnt(4) (never 0 in main loop),
// interleaved wave->row mapping so each staged half-tile is consumed by ALL
// waves in the same phase (makes counted vmcnt legal with 2 LDS buffers).

#define M_TOT 8192
#define N_TOT 4096
#define K_TOT 1024
#define QMAXF 127.0f

#define BM 256
#define BN 256
#define BK 128              // i8 elems per LDS K-tile (128 B rows)
#define NKT (K_TOT / BK)    // 8

typedef int i32x4 __attribute__((ext_vector_type(4)));

// ---------------------------------------------------------------------------
// Kernel 0: fused prep (quant blocks [0,8192), weight repack [8192,12288))
// ---------------------------------------------------------------------------
__global__ __launch_bounds__(256) void prep(const float* __restrict__ x,
                                            const int* __restrict__ w32,
                                            signed char* __restrict__ xq,
                                            signed char* __restrict__ w8,
                                            float* __restrict__ iscale) {
  const int b = blockIdx.x;
  const int t = threadIdx.x;

  if (b < M_TOT) {
    const float4 v = reinterpret_cast<const float4*>(x)[(size_t)b * 256 + t];
    float m = fmaxf(fmaxf(fabsf(v.x), fabsf(v.y)), fmaxf(fabsf(v.z), fabsf(v.w)));
#pragma unroll
    for (int off = 32; off >= 1; off >>= 1) m = fmaxf(m, __shfl_xor(m, off, 64));

    __shared__ float wmax[4];
    const int lane = t & 63, wid = t >> 6;
    if (lane == 0) wmax[wid] = m;
    __syncthreads();
    const float amax = fmaxf(fmaxf(wmax[0], wmax[1]), fmaxf(wmax[2], wmax[3]));

    float scale = amax / QMAXF;
    if (scale == 0.0f) scale = 1.0f;

    int qi;
    signed char* qb = reinterpret_cast<signed char*>(&qi);
    qb[0] = (signed char)(int)fminf(fmaxf(rintf(v.x / scale), -128.0f), 127.0f);
    qb[1] = (signed char)(int)fminf(fmaxf(rintf(v.y / scale), -128.0f), 127.0f);
    qb[2] = (signed char)(int)fminf(fmaxf(rintf(v.z / scale), -128.0f), 127.0f);
    qb[3] = (signed char)(int)fminf(fmaxf(rintf(v.w / scale), -128.0f), 127.0f);
    reinterpret_cast<int*>(xq)[(size_t)b * 256 + t] = qi;

    if (t == 0) iscale[b] = scale;
  } else {
    const int i = (b - M_TOT) * 256 + t;
    const int4 v = reinterpret_cast<const int4*>(w32)[i];
    const int packed = (v.x & 0xFF) | ((v.y & 0xFF) << 8) |
                       ((v.z & 0xFF) << 16) | (v.w << 24);
    reinterpret_cast<int*>(w8)[i] = packed;
  }
}

// ---------------------------------------------------------------------------
__device__ __forceinline__ void gload_lds16(const void* g, void* l) {
  __builtin_amdgcn_global_load_lds(
      (const __attribute__((address_space(1))) unsigned int*)g,
      (__attribute__((address_space(3))) unsigned int*)l, 16, 0, 0);
}

// 16-MFMA cluster for quadrant (h = m-half, nh = n-half), setprio-wrapped
#define MFMA16(h, nh)                                                        \
  __builtin_amdgcn_s_setprio(1);                                             \
  _Pragma("unroll") for (int j = 0; j < 4; ++j)                              \
  _Pragma("unroll") for (int jb = 0; jb < 2; ++jb)                           \
  _Pragma("unroll") for (int ks = 0; ks < 2; ++ks)                           \
      acc[(h) * 4 + j][(nh) * 2 + jb] = __builtin_amdgcn_mfma_i32_16x16x64_i8( \
          a[j * 2 + ks], bb[(nh)][jb * 2 + ks], acc[(h) * 4 + j][(nh) * 2 + jb], \
          0, 0, 0);                                                          \
  __builtin_amdgcn_s_setprio(0);

// One K-tile: 4 phases. VM0/VM1 = vmcnt immediates at P0/P1 entry (strings).
// DO_STAGE=1: stage pair0(U+1) in P0, pair1(U+1) in P1.
#define TILE(U, DO_STAGE, VM0, VM1)                                          \
  {                                                                          \
    const int c = (U) & 1;                                                   \
    /* ---- P0: quadrant (m-half0 x n-half0) ---- */                         \
    asm volatile("s_waitcnt vmcnt(" VM0 ")" ::: "memory");                   \
    __builtin_amdgcn_s_barrier();                                            \
    _Pragma("unroll") for (int j = 0; j < 4; ++j) {                          \
      a[j * 2] = rdA(c, j, 0);                                               \
      a[j * 2 + 1] = rdA(c, j, 1);                                           \
    }                                                                        \
    _Pragma("unroll") for (int jb = 0; jb < 2; ++jb) {                       \
      bb[0][jb * 2] = rdB(c, jb, 0);                                         \
      bb[0][jb * 2 + 1] = rdB(c, jb, 1);                                     \
    }                                                                        \
    if (DO_STAGE) { stA(c ^ 1, (U) + 1, 0); stB(c ^ 1, (U) + 1, 0); }        \
    asm volatile("s_waitcnt lgkmcnt(0)" ::: "memory");                       \
    __builtin_amdgcn_sched_barrier(0);                                       \
    MFMA16(0, 0)                                                             \
    /* ---- P1: (m-half0 x n-half1) ---- */                                  \
    asm volatile("s_waitcnt vmcnt(" VM1 ")" ::: "memory");                   \
    __builtin_amdgcn_s_barrier();                                            \
    _Pragma("unroll") for (int jb = 0; jb < 2; ++jb) {                       \
      bb[1][jb * 2] = rdB(c, 2 + jb, 0);                                     \
      bb[1][jb * 2 + 1] = rdB(c, 2 + jb, 1);                                 \
    }                                                                        \
    if (DO_STAGE) { stA(c ^ 1, (U) + 1, 1); stB(c ^ 1, (U) + 1, 1); }        \
    asm volatile("s_waitcnt lgkmcnt(0)" ::: "memory");                       \
    __builtin_amdgcn_sched_barrier(0);                                       \
    MFMA16(0, 1)                                                             \
    /* ---- P2: (m-half1 x n-half0) ---- */                                  \
    __builtin_amdgcn_s_barrier();                                            \
    _Pragma("unroll") for (int j = 0; j < 4; ++j) {                          \
      a[j * 2] = rdA(c, 4 + j, 0);                                           \
      a[j * 2 + 1] = rdA(c, 4 + j, 1);                                       \
    }                                                                        \
    asm volatile("s_waitcnt lgkmcnt(0)" ::: "memory");                       \
    __builtin_amdgcn_sched_barrier(0);                                       \
    MFMA16(1, 0)                                                             \
    /* ---- P3: (m-half1 x n-half1), registers only ---- */                  \
    __builtin_amdgcn_s_barrier();                                            \
    MFMA16(1, 1)                                                             \
  }

__global__ __launch_bounds__(512, 2) void int8_gemm(const signed char* __restrict__ xq,
                                                    const signed char* __restrict__ w,
                                                    const float* __restrict__ iscale,
                                                    const float* __restrict__ wscale,
                                                    const float* __restrict__ bias,
                                                    float* __restrict__ out) {
  __shared__ __attribute__((aligned(16))) signed char As[2][BM][BK];  // 64 KiB
  __shared__ __attribute__((aligned(16))) signed char Bs[2][BN][BK];  // 64 KiB

  const int t = threadIdx.x;
  const int lane = t & 63;
  const int wid = t >> 6;   // 0..7
  const int wm = wid >> 2;  // 0..1
  const int wn = wid & 3;   // 0..3

  // XCD chunking: 8m x 8n tiles per XCD -> A 2MB + B 2MB working set per L2
  const int bid = blockIdx.x;
  const int xcd = bid & 7, li = bid >> 3;          // li in [0,64)
  const int mt = (xcd >> 1) * 8 + (li >> 3);       // 0..31
  const int nt = (xcd & 1) * 8 + (li & 7);         // 0..15
  const int m0 = mt * BM, n0 = nt * BN;

  // staging: one pass = 512 thr x 16 B = 64 rows of 128 B; linear LDS dest,
  // pre-swizzled global source (involution byte ^ ((row&7)<<4))
  const int srow = t >> 3;
  const int scol_swz = ((t & 7) * 16) ^ ((srow & 7) << 4);

  // stage half h (rows h*128..h*128+127) of tile kt into buffer `buf`
  auto stA = [&](int buf, int kt, int h) {
    const int k0 = kt * BK;
#pragma unroll
    for (int cc = 0; cc < 2; ++cc) {
      const int row = h * 128 + cc * 64 + srow;
      gload_lds16(xq + (size_t)(m0 + row) * K_TOT + k0 + scol_swz,
                  &As[buf][h * 128 + cc * 64][0] + t * 16);
    }
  };
  auto stB = [&](int buf, int kt, int h) {
    const int k0 = kt * BK;
#pragma unroll
    for (int cc = 0; cc < 2; ++cc) {
      const int row = h * 128 + cc * 64 + srow;
      gload_lds16(w + (size_t)(n0 + row) * K_TOT + k0 + scol_swz,
                  &Bs[buf][h * 128 + cc * 64][0] + t * 16);
    }
  };

  // fragment reads; interleaved mapping: m-frag f -> rows f*32 + wm*16,
  // n-frag g -> rows g*64 + wn*16.  (r&7)==(lane&7) for both.
  const int lr = lane & 15;
  const int kq = (lane >> 4) * 16;
  const int sx = (lane & 7) << 4;
  auto rdA = [&](int buf, int f, int ks) -> i32x4 {
    const int r = f * 32 + wm * 16 + lr;
    return *reinterpret_cast<const i32x4*>(&As[buf][r][(ks * 64 + kq) ^ sx]);
  };
  auto rdB = [&](int buf, int g, int ks) -> i32x4 {
    const int r = g * 64 + wn * 16 + lr;
    return *reinterpret_cast<const i32x4*>(&Bs[buf][r][(ks * 64 + kq) ^ sx]);
  };

  i32x4 acc[8][4] = {};
  i32x4 a[8], bb[2][4];

  // prologue: tile 0 in stream order {pair0, pair1}
  stA(0, 0, 0); stB(0, 0, 0);   // pair0(0): Ah0, Bh0
  stA(0, 0, 1); stB(0, 0, 1);   // pair1(0): Ah1, Bh1

#pragma unroll
  for (int U = 0; U < NKT - 1; ++U) {
    TILE(U, 1, "4", "4")
  }
  TILE(NKT - 1, 0, "4", "0")

  // ---- epilogue: C/D layout col=lane&15, row=(lane>>4)*4+i (validated) ----
  const int col = lane & 15;
  const int rq = lane >> 4;
  float wsc[4], bv[4];
#pragma unroll
  for (int g = 0; g < 4; ++g) {
    const int gn = n0 + g * 64 + wn * 16 + col;
    wsc[g] = wscale[gn];
    bv[g] = bias[gn];
  }
#pragma unroll
  for (int f = 0; f < 8; ++f) {
    const int gmb = m0 + f * 32 + wm * 16 + rq * 4;
#pragma unroll
    for (int i = 0; i < 4; ++i) {
      const int gm = gmb + i;
      const float isc = iscale[gm];
      float* rowp = out + (size_t)gm * N_TOT + n0 + wn * 16 + col;
#pragma unroll
      for (int g = 0; g < 4; ++g)
        __builtin_nontemporal_store((float)acc[f][g][i] * wsc[g] * isc + bv[g],
                                    rowp + g * 64);
    }
  }
}

// ---------------------------------------------------------------------------
extern "C" void kernel_launch(void* const* d_in, const int* in_sizes, int n_in,
                              void* d_out, int out_size, void* d_ws, size_t ws_size,
                              hipStream_t stream) {
  const float* x = (const float*)d_in[0];
  const int* w32 = (const int*)d_in[1];
  const float* wscale = (const float*)d_in[2];
  const float* bias = (const float*)d_in[3];
  float* out = (float*)d_out;

  signed char* xq = (signed char*)d_ws;                                    // 8 MB
  float* iscale = (float*)((char*)d_ws + (size_t)M_TOT * K_TOT);           // 32 KB
  signed char* w8 = (signed char*)((char*)d_ws + (size_t)M_TOT * K_TOT + M_TOT * 4);  // 4 MB

  const int pack_blocks = (N_TOT * K_TOT / 4) / 256;
  prep<<<M_TOT + pack_blocks, 256, 0, stream>>>(x, w32, xq, w8, iscale);
  int8_gemm<<<dim3((M_TOT / BM) * (N_TOT / BN)), 512, 0, stream>>>(xq, w8, iscale, wscale, bias, out);
}